// Round 17
// baseline (178.648 us; speedup 1.0000x reference)
//
#include <hip/hip_runtime.h>
#include <cstddef>

typedef unsigned short u16;
typedef unsigned char u8;
typedef unsigned u32;
typedef float f32x4 __attribute__((ext_vector_type(4)));
typedef u16 u16x4 __attribute__((ext_vector_type(4)));
typedef u16 u16x8 __attribute__((ext_vector_type(8)));
typedef u8 u8x8 __attribute__((ext_vector_type(8)));
typedef __bf16 bf16x8 __attribute__((ext_vector_type(8)));
typedef int i32x4 __attribute__((ext_vector_type(4)));
typedef int i32x8 __attribute__((ext_vector_type(8)));
typedef long lx2 __attribute__((ext_vector_type(2)));

__device__ __forceinline__ u16 f2bf(float f) {
  u32 u = __builtin_bit_cast(u32, f);
  u += 0x7fffu + ((u >> 16) & 1u);   // RTNE
  return (u16)(u >> 16);
}
__device__ __forceinline__ float bf2f(u16 h) {
  return __builtin_bit_cast(float, ((u32)h) << 16);
}
__device__ __forceinline__ u8 f2fp8(float v) {
  int t = __builtin_amdgcn_cvt_pk_fp8_f32(v, v, 0, false);
  return (u8)(t & 0xff);
}
__device__ __forceinline__ void gld_lds16(const void* g, void* l) {
  __builtin_amdgcn_global_load_lds((const __attribute__((address_space(1))) void*)g,
                                   (__attribute__((address_space(3))) void*)l, 16, 0, 0);
}

// ---------------- all f32->bf16 converts + L-zero in ONE launch ----------------
__global__ __launch_bounds__(256) void cvt_all(
    const float* __restrict__ q, const float* __restrict__ k, const float* __restrict__ v,
    const float* __restrict__ w5, const float* __restrict__ w3,
    const float* __restrict__ w7, const float* __restrict__ w9,
    u16* __restrict__ o_q, u16* __restrict__ o_k, u16* __restrict__ o_v,
    u16* __restrict__ o_wq, u16* __restrict__ o_wk, u16* __restrict__ o_wv,
    u16* __restrict__ o_ow, float* __restrict__ Lz)
{
  int b = blockIdx.x;
  if (b >= 5632) {                     // zero the 16384-float L buffer
    f32x4 z4 = 0.0f;
    float* p = Lz + threadIdx.x * 64;
#pragma unroll
    for (int j = 0; j < 16; ++j) *(f32x4*)(p + j * 4) = z4;
    return;
  }
  const float* in; u16* out; int base; bool perm = false;
  if      (b < 512)  { in = q;  out = o_q;  base = b; }
  else if (b < 1024) { in = k;  out = o_k;  base = b - 512; }
  else if (b < 1536) { in = v;  out = o_v;  base = b - 1024; }
  else if (b < 2560) { in = w5; out = o_wq; base = b - 1536; }
  else if (b < 3584) { in = w3; out = o_wk; base = b - 2560; }
  else if (b < 4608) { in = w7; out = o_wv; base = b - 3584; }
  else               { in = w9; out = o_ow; base = b - 4608; perm = true; }
  int i = (base * 256 + threadIdx.x) * 8;
  u16x8 o;
  if (!perm) {
    f32x4 a = *(const f32x4*)(in + i);
    f32x4 c = *(const f32x4*)(in + i + 4);
    o[0] = f2bf(a[0]); o[1] = f2bf(a[1]); o[2] = f2bf(a[2]); o[3] = f2bf(a[3]);
    o[4] = f2bf(c[0]); o[5] = f2bf(c[1]); o[6] = f2bf(c[2]); o[7] = f2bf(c[3]);
  } else {
    // within-64 K-group permutation: pos t <- true (t&3)*16+(t>>2)
    int row = i >> 12, col0 = i & 4095;
    int group = col0 & ~63, t0 = col0 & 63;
    const float* rp = in + ((size_t)row << 12) + group;
#pragma unroll
    for (int j = 0; j < 8; ++j) {
      int t = t0 + j;
      o[j] = f2bf(rp[((t & 3) << 4) + (t >> 2)]);
    }
  }
  *(u16x8*)(out + i) = o;
}

// =====================================================================
// bf16 pipelined 128x128 B^T GEMM — ALL THREE projections, one launch.
// (256,4): VGPR cap 128 -> 4 blk/CU with the 33KB LDS (was (256,2)).
// =====================================================================
__global__ __launch_bounds__(256, 4) void gemm_proj(
    const u16* __restrict__ Aq, const u16* __restrict__ Ak, const u16* __restrict__ Av,
    const u16* __restrict__ Bq, const u16* __restrict__ Bk, const u16* __restrict__ Bv,
    u8* __restrict__ Cq, u8* __restrict__ Ck, u8* __restrict__ Cvv,
    const float* __restrict__ bq, const float* __restrict__ bk, const float* __restrict__ bv,
    int N, int K)
{
  __shared__ alignas(16) char smem[33024];

  const int tid = threadIdx.x, lid = tid & 63, wid = tid >> 6;
  const int wm = wid >> 1, wn = wid & 1;
  const int g = lid >> 4, r16 = lid & 15;
  const int which = blockIdx.z;

  const u16* A = (which == 0) ? Aq : (which == 1) ? Ak : Av;
  const u16* B = (which == 0) ? Bq : (which == 1) ? Bk : Bv;
  u8* C = (which == 0) ? Cq : (which == 1) ? Ck : Cvv;
  const float* bias = (which == 0) ? bq : (which == 1) ? bk : bv;

  const int nx = gridDim.x, ny = gridDim.y;
  const int lin = blockIdx.x + nx * blockIdx.y;
  const int xcd = lin & 7, slot = lin >> 3;
  const int wx = slot % nx;
  const int c_ = xcd + (slot / nx) * 8;
  const int m0 = (c_ % ny) * 128, n0 = wx * 128;

  const int NT = K >> 5;

  int offA[4], offB[4];
#pragma unroll
  for (int f = 0; f < 4; ++f) {
    int ra = wm * 64 + f * 16 + r16;
    offA[f] = ra * 64 + ((g ^ ((ra >> 1) & 3)) << 4);
    int rb = wn * 64 + f * 16 + r16;
    offB[f] = rb * 64 + ((g ^ ((rb >> 1) & 3)) << 4);
  }

  auto stage_tile = [&](int ts) {
    char* base = smem + (ts & 1) * 16384;
    const u16* At = A + (size_t)ts * 32;
    const u16* Bt = B + (size_t)ts * 32;
#pragma unroll
    for (int l = 0; l < 2; ++l) {
      int i = l * 256 + tid;
      int row = i >> 2, x = i & 3;
      int c = x ^ ((row >> 1) & 3);
      gld_lds16(At + (size_t)(m0 + row) * K + c * 8, base + i * 16);
    }
#pragma unroll
    for (int l = 0; l < 2; ++l) {
      int i = l * 256 + tid;
      int row = i >> 2, x = i & 3;
      int c = x ^ ((row >> 1) & 3);
      gld_lds16(Bt + (size_t)(n0 + row) * K + c * 8, base + 8192 + i * 16);
    }
  };

  f32x4 acc[4][4];
#pragma unroll
  for (int i = 0; i < 4; ++i)
#pragma unroll
    for (int j = 0; j < 4; ++j) acc[i][j] = 0.0f;

  stage_tile(0);
  stage_tile(1);
  asm volatile("s_waitcnt vmcnt(4)" ::: "memory");
  __builtin_amdgcn_s_barrier();

  for (int t = 0; t < NT; ++t) {
    const char* Ab = smem + (t & 1) * 16384;
    const char* Bb = Ab + 8192;
    bf16x8 ar[4], br[4];
#pragma unroll
    for (int f = 0; f < 4; ++f) ar[f] = *(const bf16x8*)(Ab + offA[f]);
#pragma unroll
    for (int f = 0; f < 4; ++f) br[f] = *(const bf16x8*)(Bb + offB[f]);
    asm volatile("s_waitcnt lgkmcnt(0)" ::: "memory");
    __builtin_amdgcn_s_barrier();
    if (t + 2 < NT) stage_tile(t + 2);
    __builtin_amdgcn_s_setprio(1);
#pragma unroll
    for (int mf = 0; mf < 4; ++mf)
#pragma unroll
      for (int nf = 0; nf < 4; ++nf)
        acc[mf][nf] = __builtin_amdgcn_mfma_f32_16x16x32_bf16(ar[mf], br[nf], acc[mf][nf], 0, 0, 0);
    __builtin_amdgcn_s_setprio(0);
    if (t + 2 < NT) asm volatile("s_waitcnt vmcnt(4)" ::: "memory");
    else            asm volatile("s_waitcnt vmcnt(0)" ::: "memory");
    __builtin_amdgcn_s_barrier();
  }

  if (which < 2) {
    const int hh = (n0 + wn * 64) >> 9;
    const int d2g = (n0 & 511) + wn * 64;
#pragma unroll
    for (int mf = 0; mf < 4; ++mf)
#pragma unroll
      for (int r = 0; r < 4; ++r) {
        int gm = m0 + wm * 64 + mf * 16 + (g << 2) + r;
        int b = gm >> 9, s = gm & 511;
        float v0 = acc[mf][0][r] + bias[n0 + wn * 64 + 0 * 16 + r16];
        float v1 = acc[mf][1][r] + bias[n0 + wn * 64 + 1 * 16 + r16];
        float v2 = acc[mf][2][r] + bias[n0 + wn * 64 + 2 * 16 + r16];
        float v3 = acc[mf][3][r] + bias[n0 + wn * 64 + 3 * 16 + r16];
        int pk = __builtin_amdgcn_cvt_pk_fp8_f32(v0, v1, 0, false);
        pk = __builtin_amdgcn_cvt_pk_fp8_f32(v2, v3, pk, true);
        int row = (which == 0) ? ((s << 3) + hh) : ((hh << 9) + s);
        *(u32*)(C + (size_t)b * 2097152 + (size_t)row * 512 + d2g + r16 * 4) = (u32)pk;
      }
  } else {
    u16* E = (u16*)smem;   // 128 x 129 bf16
#pragma unroll
    for (int mf = 0; mf < 4; ++mf)
#pragma unroll
      for (int nf = 0; nf < 4; ++nf)
#pragma unroll
        for (int r = 0; r < 4; ++r) {
          int lm = wm * 64 + mf * 16 + (g << 2) + r;
          int ln = wn * 64 + nf * 16 + r16;
          E[lm * 129 + ln] = f2bf(acc[mf][nf][r] + bias[n0 + ln]);
        }
    __syncthreads();
    int b = m0 >> 9, s0 = m0 & 511, hh = n0 >> 9, d20 = n0 & 511;
    int c = tid >> 1;
    int r0 = (tid & 1) * 64;
    u8* dst = C + (size_t)b * 2097152 + (size_t)(d20 + c) * 4096 + (hh << 9) + s0 + r0;
#pragma unroll
    for (int i = 0; i < 64; i += 8) {
      u8x8 p;
#pragma unroll
      for (int jj = 0; jj < 8; ++jj) {
        int t = i + jj;
        int sl = r0 + ((t & 3) << 4) + (t >> 2);
        p[jj] = f2fp8(bf2f(E[sl * 129 + c]));
      }
      *(u8x8*)(dst + i) = p;
    }
  }
}

// =====================================================================
// fp8 pipelined 128x128 B^T GEMM — SCORES (proven: 74 µs, 0 conflicts).
// =====================================================================
__global__ __launch_bounds__(256, 4) void gemm_f8s(
    const u8* __restrict__ A, const u8* __restrict__ B, u8* __restrict__ Cv,
    float* __restrict__ Lbuf, int N, int K, float scale,
    long bsA, long bsB, long bsC)
{
  constexpr int SLOT = 256 * 64;
  __shared__ alignas(16) char smem[2 * SLOT];

  const int tid = threadIdx.x, lid = tid & 63, wid = tid >> 6;
  const int wm = wid >> 1, wn = wid & 1;
  const int g = lid >> 4, r16 = lid & 15;

  const int nx = gridDim.x, ny = gridDim.y;
  const int lin = blockIdx.x + nx * (blockIdx.y + ny * blockIdx.z);
  const int xcd = lin & 7, slot = lin >> 3;
  const int wx = slot % nx;
  const int c_ = xcd + (slot / nx) * 8;
  const int m0 = (c_ % ny) * 128, n0 = wx * 128, z = c_ / ny;

  A += (size_t)z * bsA;
  B += (size_t)z * bsB;
  const int NT = K >> 6;

  int offA[4], offB[4];
#pragma unroll
  for (int f = 0; f < 4; ++f) {
    int ra = wm * 64 + f * 16 + r16;
    offA[f] = ra * 64 + ((g ^ ((ra >> 1) & 3)) << 4);
    int rb = wn * 64 + f * 16 + r16;
    offB[f] = rb * 64 + ((g ^ ((rb >> 1) & 3)) << 4);
  }

  auto stage_tile = [&](int ts) {
    char* base = smem + (ts & 1) * SLOT;
    const u8* At = A + (size_t)ts * 64;
    const u8* Bt = B + (size_t)ts * 64;
#pragma unroll
    for (int l = 0; l < 2; ++l) {
      int i = l * 256 + tid;
      int row = i >> 2, x = i & 3;
      int c = x ^ ((row >> 1) & 3);
      gld_lds16(At + (size_t)(m0 + row) * K + c * 16, base + i * 16);
    }
#pragma unroll
    for (int l = 0; l < 2; ++l) {
      int i = l * 256 + tid;
      int row = i >> 2, x = i & 3;
      int c = x ^ ((row >> 1) & 3);
      gld_lds16(Bt + (size_t)(n0 + row) * K + c * 16, base + 8192 + i * 16);
    }
  };

  f32x4 acc[4][4];
#pragma unroll
  for (int i = 0; i < 4; ++i)
#pragma unroll
    for (int j = 0; j < 4; ++j) acc[i][j] = 0.0f;

  stage_tile(0);
  stage_tile(1);
  asm volatile("s_waitcnt vmcnt(4)" ::: "memory");
  __builtin_amdgcn_s_barrier();

  for (int t = 0; t < NT; ++t) {
    const char* Ab = smem + (t & 1) * SLOT;
    const char* Bb = Ab + 8192;
    lx2 ar[4], br[4];
#pragma unroll
    for (int f = 0; f < 4; ++f) ar[f] = *(const lx2*)(Ab + offA[f]);
#pragma unroll
    for (int f = 0; f < 4; ++f) br[f] = *(const lx2*)(Bb + offB[f]);
    asm volatile("s_waitcnt lgkmcnt(0)" ::: "memory");
    __builtin_amdgcn_s_barrier();
    if (t + 2 < NT) stage_tile(t + 2);
    __builtin_amdgcn_s_setprio(1);
#pragma unroll
    for (int mf = 0; mf < 4; ++mf)
#pragma unroll
      for (int nf = 0; nf < 4; ++nf) {
        acc[mf][nf] = __builtin_amdgcn_mfma_f32_16x16x32_fp8_fp8(ar[mf][0], br[nf][0], acc[mf][nf], 0, 0, 0);
        acc[mf][nf] = __builtin_amdgcn_mfma_f32_16x16x32_fp8_fp8(ar[mf][1], br[nf][1], acc[mf][nf], 0, 0, 0);
      }
    __builtin_amdgcn_s_setprio(0);
    if (t + 2 < NT) asm volatile("s_waitcnt vmcnt(4)" ::: "memory");
    else            asm volatile("s_waitcnt vmcnt(0)" ::: "memory");
    __builtin_amdgcn_s_barrier();
  }

  u8* Cp = Cv + (size_t)z * bsC;
  float* Lp = Lbuf + (size_t)z * 4096;
#pragma unroll
  for (int mf = 0; mf < 4; ++mf) {
#pragma unroll
    for (int r = 0; r < 4; ++r) {
      int gm = m0 + wm * 64 + mf * 16 + (g << 2) + r;
      float p0 = __expf(acc[mf][0][r] * scale);
      float p1 = __expf(acc[mf][1][r] * scale);
      float p2 = __expf(acc[mf][2][r] * scale);
      float p3 = __expf(acc[mf][3][r] * scale);
      float rs = (p0 + p1) + (p2 + p3);
      int pk = __builtin_amdgcn_cvt_pk_fp8_f32(p0, p1, 0, false);
      pk = __builtin_amdgcn_cvt_pk_fp8_f32(p2, p3, pk, true);
      *(u32*)(Cp + (size_t)gm * N + n0 + wn * 64 + r16 * 4) = (u32)pk;
      rs += __shfl_xor(rs, 1); rs += __shfl_xor(rs, 2);
      rs += __shfl_xor(rs, 4); rs += __shfl_xor(rs, 8);
      if (r16 == 0) atomicAdd(&Lp[gm], rs);
    }
  }
}

// =====================================================================
// MX-scaled fp8 pipelined 128x128 B^T GEMM — PV (proven ~30 µs).
// =====================================================================
__global__ __launch_bounds__(512, 4) void gemm_mx_pv(
    const u8* __restrict__ A, const u8* __restrict__ B, u16* __restrict__ Cv,
    const float* __restrict__ Lbuf, int N, int K,
    long bsA, long bsB, long bsC)
{
  __shared__ alignas(16) char smem[65536];

  const int tid = threadIdx.x, lid = tid & 63, wid = tid >> 6;
  const int wm = wid >> 1, wn = wid & 1;
  const int g = lid >> 4, r16 = lid & 15;

  const int nx = gridDim.x, ny = gridDim.y;
  const int lin = blockIdx.x + nx * (blockIdx.y + ny * blockIdx.z);
  const int xcd = lin & 7, slot = lin >> 3;
  const int wx = slot % nx;
  const int c_ = xcd + (slot / nx) * 8;
  const int m0 = (c_ % ny) * 128, n0 = wx * 128, z = c_ / ny;

  A += (size_t)z * bsA;
  B += (size_t)z * bsB;
  const int NT = K >> 7;

  int offA[2], offB[4];
#pragma unroll
  for (int f = 0; f < 2; ++f) {
    int ra = wm * 32 + f * 16 + r16;
    offA[f] = ra * 64 + ((g ^ ((ra >> 1) & 3)) << 4);
  }
#pragma unroll
  for (int f = 0; f < 4; ++f) {
    int rb = wn * 64 + f * 16 + r16;
    offB[f] = rb * 64 + ((g ^ ((rb >> 1) & 3)) << 4);
  }

  auto stage_tile = [&](int ts) {
    char* base = smem + (ts & 1) * 32768;
    const u8* At = A + (size_t)ts * 128;
    const u8* Bt = B + (size_t)ts * 128;
#pragma unroll
    for (int l = 0; l < 2; ++l) {
      int i = l * 512 + tid;
      int half = i >> 9, rem = i & 511, row = rem >> 2, x = rem & 3;
      int c = x ^ ((row >> 1) & 3);
      gld_lds16(At + (size_t)(m0 + row) * K + half * 64 + c * 16,
                base + half * 8192 + rem * 16);
    }
#pragma unroll
    for (int l = 0; l < 2; ++l) {
      int i = l * 512 + tid;
      int half = i >> 9, rem = i & 511, row = rem >> 2, x = rem & 3;
      int c = x ^ ((row >> 1) & 3);
      gld_lds16(Bt + (size_t)(n0 + row) * K + half * 64 + c * 16,
                base + 16384 + half * 8192 + rem * 16);
    }
  };

  f32x4 acc[2][4];
#pragma unroll
  for (int i = 0; i < 2; ++i)
#pragma unroll
    for (int j = 0; j < 4; ++j) acc[i][j] = 0.0f;

  stage_tile(0);
  stage_tile(1);
  asm volatile("s_waitcnt vmcnt(4)" ::: "memory");
  __builtin_amdgcn_s_barrier();

  for (int t = 0; t < NT; ++t) {
    const char* Ab = smem + (t & 1) * 32768;
    const char* Bb = Ab + 16384;
    i32x8 af[2], bfr[4];
#pragma unroll
    for (int f = 0; f < 2; ++f) {
      i32x4 lo = *(const i32x4*)(Ab + offA[f]);
      i32x4 hi = *(const i32x4*)(Ab + 8192 + offA[f]);
      af[f] = __builtin_shufflevector(lo, hi, 0, 1, 2, 3, 4, 5, 6, 7);
    }
#pragma unroll
    for (int f = 0; f < 4; ++f) {
      i32x4 lo = *(const i32x4*)(Bb + offB[f]);
      i32x4 hi = *(const i32x4*)(Bb + 8192 + offB[f]);
      bfr[f] = __builtin_shufflevector(lo, hi, 0, 1, 2, 3, 4, 5, 6, 7);
    }
    asm volatile("s_waitcnt lgkmcnt(0)" ::: "memory");
    __builtin_amdgcn_s_barrier();
    if (t + 2 < NT) stage_tile(t + 2);
    __builtin_amdgcn_s_setprio(1);
#pragma unroll
    for (int mf = 0; mf < 2; ++mf)
#pragma unroll
      for (int nf = 0; nf < 4; ++nf)
        acc[mf][nf] = __builtin_amdgcn_mfma_scale_f32_16x16x128_f8f6f4(
            af[mf], bfr[nf], acc[mf][nf],
            0, 0, 0, 0x7F7F7F7F, 0, 0x7F7F7F7F);
    __builtin_amdgcn_s_setprio(0);
    if (t + 2 < NT) asm volatile("s_waitcnt vmcnt(4)" ::: "memory");
    else            asm volatile("s_waitcnt vmcnt(0)" ::: "memory");
    __builtin_amdgcn_s_barrier();
  }

  u16* C = Cv + (size_t)z * bsC;
  const float* Lp = Lbuf + (size_t)z * 4096;
#pragma unroll
  for (int mf = 0; mf < 2; ++mf) {
#pragma unroll
    for (int r = 0; r < 4; ++r) {
      int gm = m0 + wm * 32 + mf * 16 + (g << 2) + r;
      float inv = 1.0f / Lp[gm];
      u16x4 o;
#pragma unroll
      for (int nf = 0; nf < 4; ++nf) o[nf] = f2bf(acc[mf][nf][r] * inv);
      *(u16x4*)(C + (size_t)(gm >> 3) * 4096 + (size_t)(gm & 7) * 512 +
                n0 + wn * 64 + r16 * 4) = o;
    }
  }
}

// =====================================================================
// FINAL projection, split-K=4 (proven), then reduce + bias.
// =====================================================================
__global__ __launch_bounds__(256, 2) void gemm_fpart(
    const u16* __restrict__ A0, const u16* __restrict__ B0,
    float* __restrict__ part, int K)
{
  __shared__ alignas(16) char smem[32768];

  const int tid = threadIdx.x, lid = tid & 63, wid = tid >> 6;
  const int wm = wid >> 1, wn = wid & 1;
  const int g = lid >> 4, r16 = lid & 15;
  const int m0 = blockIdx.y * 128, n0 = blockIdx.x * 128, z = blockIdx.z;

  const u16* A = A0 + (size_t)z * 1024;
  const u16* B = B0 + (size_t)z * 1024;
  constexpr int NT = 32;

  int offA[4], offB[4];
#pragma unroll
  for (int f = 0; f < 4; ++f) {
    int ra = wm * 64 + f * 16 + r16;
    offA[f] = ra * 64 + ((g ^ ((ra >> 1) & 3)) << 4);
    int rb = wn * 64 + f * 16 + r16;
    offB[f] = rb * 64 + ((g ^ ((rb >> 1) & 3)) << 4);
  }

  auto stage_tile = [&](int ts) {
    char* base = smem + (ts & 1) * 16384;
    const u16* At = A + (size_t)ts * 32;
    const u16* Bt = B + (size_t)ts * 32;
#pragma unroll
    for (int l = 0; l < 2; ++l) {
      int i = l * 256 + tid;
      int row = i >> 2, x = i & 3;
      int c = x ^ ((row >> 1) & 3);
      gld_lds16(At + (size_t)(m0 + row) * K + c * 8, base + i * 16);
    }
#pragma unroll
    for (int l = 0; l < 2; ++l) {
      int i = l * 256 + tid;
      int row = i >> 2, x = i & 3;
      int c = x ^ ((row >> 1) & 3);
      gld_lds16(Bt + (size_t)(n0 + row) * K + c * 8, base + 8192 + i * 16);
    }
  };

  f32x4 acc[4][4];
#pragma unroll
  for (int i = 0; i < 4; ++i)
#pragma unroll
    for (int j = 0; j < 4; ++j) acc[i][j] = 0.0f;

  stage_tile(0);
  stage_tile(1);
  asm volatile("s_waitcnt vmcnt(4)" ::: "memory");
  __builtin_amdgcn_s_barrier();

  for (int t = 0; t < NT; ++t) {
    const char* Ab = smem + (t & 1) * 16384;
    const char* Bb = Ab + 8192;
    bf16x8 ar[4], br[4];
#pragma unroll
    for (int f = 0; f < 4; ++f) ar[f] = *(const bf16x8*)(Ab + offA[f]);
#pragma unroll
    for (int f = 0; f < 4; ++f) br[f] = *(const bf16x8*)(Bb + offB[f]);
    asm volatile("s_waitcnt lgkmcnt(0)" ::: "memory");
    __builtin_amdgcn_s_barrier();
    if (t + 2 < NT) stage_tile(t + 2);
    __builtin_amdgcn_s_setprio(1);
#pragma unroll
    for (int mf = 0; mf < 4; ++mf)
#pragma unroll
      for (int nf = 0; nf < 4; ++nf)
        acc[mf][nf] = __builtin_amdgcn_mfma_f32_16x16x32_bf16(ar[mf], br[nf], acc[mf][nf], 0, 0, 0);
    __builtin_amdgcn_s_setprio(0);
    if (t + 2 < NT) asm volatile("s_waitcnt vmcnt(4)" ::: "memory");
    else            asm volatile("s_waitcnt vmcnt(0)" ::: "memory");
    __builtin_amdgcn_s_barrier();
  }

  float* P = part + ((size_t)z << 20);
#pragma unroll
  for (int mf = 0; mf < 4; ++mf)
#pragma unroll
    for (int nf = 0; nf < 4; ++nf)
#pragma unroll
      for (int r = 0; r < 4; ++r) {
        int gm = m0 + wm * 64 + mf * 16 + (g << 2) + r;
        int gn = n0 + wn * 64 + nf * 16 + r16;
        P[(size_t)gm * 512 + gn] = acc[mf][nf][r];
      }
}

// ---- reduce 4 partials + bias -> out (f32), 4 elems/thread ----
__global__ __launch_bounds__(256) void fin_reduce(
    const float* __restrict__ part, const float* __restrict__ bias,
    float* __restrict__ out)
{
  int i = (blockIdx.x * 256 + threadIdx.x) * 4;
  f32x4 s = *(const f32x4*)(part + i);
  s += *(const f32x4*)(part + 1048576 + i);
  s += *(const f32x4*)(part + 2097152 + i);
  s += *(const f32x4*)(part + 3145728 + i);
  s += *(const f32x4*)(bias + (i & 511));
  *(f32x4*)(out + i) = s;
}

// ---------------------------------------------------------------------------
extern "C" void kernel_launch(void* const* d_in, const int* in_sizes, int n_in,
                              void* d_out, int out_size, void* d_ws, size_t ws_size,
                              hipStream_t stream) {
  (void)in_sizes; (void)n_in; (void)out_size; (void)ws_size;
  const float* q_f  = (const float*)d_in[0];
  const float* k_f  = (const float*)d_in[1];
  const float* v_f  = (const float*)d_in[2];
  const float* wq_b = (const float*)d_in[4];
  const float* wk_b = (const float*)d_in[6];
  const float* wv_b = (const float*)d_in[8];
  const float* ou_b = (const float*)d_in[10];
  float* out = (float*)d_out;

  char* ws = (char*)d_ws;
  u16* q_bf  = (u16*)(ws + 0);          // 2MB  bf16(q)
  u16* k_bf  = (u16*)(ws + 2097152);    // 2MB
  u16* v_bf  = (u16*)(ws + 4194304);    // 2MB
  u16* wA_q  = (u16*)(ws + 6291456);    // 4MB  bf16(wk_w) (reference swap)
  u16* wA_k  = (u16*)(ws + 10485760);   // 4MB  bf16(wq_w)
  u16* wA_v  = (u16*)(ws + 14680064);   // 4MB  bf16(wv_w)
  u16* ow_bf = (u16*)(ws + 18874368);   // 4MB  bf16(out_w), K within-64 permuted
  u8*  qp    = (u8*)(ws + 23068672);    // 8MB  (4,4096,512) fp8, l=s*8+h, d2 permuted
  u8*  kp    = (u8*)(ws + 31457280);    // 8MB  (4,4096,512) fp8, l'=h*512+s, d2 permuted
  u8*  vpt   = (u8*)(ws + 39845888);    // 8MB  (4,512,4096) fp8, [d2][kv-permuted]
  u16* oflat = (u16*)(ws + 48234496);   // 16MB (4,512,4096) bf16, cols within-64 permuted
  u8*  P     = (u8*)(ws + 65011712);    // 64MB (4,4096,4096) fp8, cols kv-permuted
  float* fpt = (float*)(ws + 132120576);// 16MB (4,2048,512) f32 split-K partials

  float* L = (float*)d_out;  // 64KB row-sums; dead until fin_reduce overwrites

  // all converts + L-zero in one launch
  cvt_all<<<5633, 256, 0, stream>>>(
      q_f, k_f, v_f, (const float*)d_in[5], (const float*)d_in[3],
      (const float*)d_in[7], (const float*)d_in[9],
      q_bf, k_bf, v_bf, wA_q, wA_k, wA_v, ow_bf, L);

  // all three projections in one launch (reference swap: qp uses wk, kp uses wq)
  gemm_proj<<<dim3(32,16,3), 256, 0, stream>>>(
      q_bf, k_bf, v_bf, wA_q, wA_k, wA_v, qp, kp, vpt, wk_b, wq_b, wv_b, 4096, 512);

  const float scl = 0.04419417382415922f;  // 1/sqrt(512)
  // scores: P = exp(s*scl) fp8 (kv-permuted) + row-sums into L  (fp8, NT=8)
  gemm_f8s<<<dim3(32,32,4), 256, 0, stream>>>(qp, kp, P, L, 4096, 512, scl,
                                              2097152, 2097152, 16777216);
  // PV: O = (P @ V) / L -> oflat bf16  (MX fp8, K=128, NT=32)
  gemm_mx_pv<<<dim3(4,32,4), 512, 0, stream>>>(P, vpt, oflat, L, 512, 4096,
                                               16777216, 2097152, 2097152);
  // final projection: split-K=4 partials, then reduce + bias
  gemm_fpart<<<dim3(4,16,4), 256, 0, stream>>>(oflat, ow_bf, fpt, 4096);
  fin_reduce<<<1024, 256, 0, stream>>>(fpt, ou_b, out);
}